// Round 2
// baseline (227.731 us; speedup 1.0000x reference)
//
#include <hip/hip_runtime.h>

namespace {
constexpr int kB = 4, kC = 32, kH = 512, kW = 512, kN = 64;
constexpr int kHout = 16, kMaxW = 192;
constexpr long long kResultElems = (long long)kB * kN * kC * kHout * kMaxW;
constexpr int kWaves = 3;                    // 192 threads
}

// One block per (b, n, i); 3 waves. BARRIER-FREE: each wave owns channels
// {w, w+3, ...}, stages the two bilinear source rows (y0,y1) for its channel
// into its PRIVATE LDS region with coalesced float4 loads, then samples all
// 192 output columns itself (3 chunks of 64 lanes). No __syncthreads -- no
// vmcnt(0) drain points, no cross-wave coupling; 30 independent waves/CU hide
// LLC/L2 latency by TLP.
//
// R6 = round-0 structure + XCD swizzle ONLY (decomposition round).
//  - R5's nt stores REVERTED: image+output (229 MB) fit in the 256 MB LLC,
//    and cached output lines can be overwritten in-LLC by the harness's
//    poison fill before writeback -- nt defeated that absorption and forced
//    101 MB of HBM writes (the R5 regression).
//  - R5's register prefetch REVERTED: 30 waves/CU x ~3KB in flight already
//    saturates the memory system; ILP prefetch is redundant with TLP.
//  - XCD swizzle KEPT: blockIdx round-robins XCDs (blk%8); remap so each XCD
//    owns 32 contiguous bn with the 16 i-blocks of a bn adjacent -> their
//    shared source rows become same-XCD L2 hits.
extern "C" __global__ __launch_bounds__(kWaves * 64) void roi_rotate(
    const float* __restrict__ image,
    const float* __restrict__ boxes,
    float* __restrict__ result,
    float* __restrict__ mask)
{
    __shared__ float ls[kWaves][2][kW];      // 12 KiB, wave-private regions

    // XCD-aware decode: grid = 4096 = 8 xcd * 32 bn * 16 i.
    const int blk  = blockIdx.x;
    const int xcd  = blk & 7;                // hw round-robin xcd id (m09)
    const int slot = blk >> 3;               // dispatch order within xcd
    const int bn   = (xcd << 5) | (slot >> 4);   // 32 bn per xcd, i adjacent
    const int i    = slot & 15;              // output row 0..15
    const int b    = bn >> 6;

    const int tid  = threadIdx.x;
    const int w    = tid >> 6;               // wave id 0..2
    const int lane = tid & 63;

    const float* bx = boxes + bn * 5;
    const float left = bx[0];
    const float top  = bx[1];
    const float bw   = __fsub_rn(bx[2], bx[0]);
    const float bh   = __fsub_rn(bx[3], bx[1]);
    const int width  = (int)(__fmul_rn(__fdiv_rn(bw, bh), (float)kHout));
    const float each_w = __fdiv_rn(bw, (float)(width - 1));
    const float each_h = __fdiv_rn(bh, (float)(kHout - 1));

    // y taps: uniform over the block (depend only on i).
    const float y = __fadd_rn(__fmul_rn((float)i, each_h), top);
    const int yf = (int)floorf(y);
    const int y0 = min(max(yf,     0), kH - 1);
    const int y1 = min(max(yf + 1, 0), kH - 1);
    const float wy1 = (float)y1 - y;
    const float wy0 = y - (float)y0;

    // Staging extent (block-uniform). For valid j: x in [left, left+bw], so
    // x0 >= xlo and x1 <= xhi. float4 tails over-read <= 3 floats and stay
    // inside the image allocation.
    const int xlo = (min(max((int)floorf(left), 0), kW - 1)) & ~3;  // 16B align
    const int xhi = min((int)floorf(__fadd_rn(left, bw)) + 1, kW - 1);
    const int S   = xhi - xlo + 1;           // <= 512

    // Per-lane x taps for its 3 output columns j = 64q + lane.
    int   lx0q[3], lx1q[3];
    float waq[3], wbq[3], wcq[3], wdq[3];
    bool  vq[3];
    #pragma unroll
    for (int q = 0; q < 3; ++q) {
        const int j = 64 * q + lane;
        const float x = __fadd_rn(__fmul_rn((float)j, each_w), left);
        const int xf = (int)floorf(x);
        const int x0 = min(max(xf,     0), kW - 1);
        const int x1 = min(max(xf + 1, 0), kW - 1);
        const float wx1 = (float)x1 - x;
        const float wx0 = x - (float)x0;
        lx0q[q] = x0 - xlo;
        lx1q[q] = x1 - xlo;
        waq[q] = wx1 * wy1;
        wbq[q] = wx1 * wy0;
        wcq[q] = wx0 * wy1;
        wdq[q] = wx0 * wy0;
        vq[q]  = (j < width);
    }

    // Staging: lane covers 16B chunks at float offsets 4*lane and 4*(lane+64).
    const bool need0 = (4 * lane        < S);
    const bool need1 = (4 * (lane + 64) < S);
    const int  o0 = 4 * lane;
    const int  o1 = 4 * (lane + 64);
    const size_t r0 = (size_t)y0 * kW + xlo;
    const size_t r1 = (size_t)y1 * kW + xlo;

    const float* chbase = image + (size_t)b * ((size_t)kC * kH * kW);
    constexpr size_t kChStride = (size_t)kH * kW;
    float* opb = result + (size_t)bn * (kC * kHout * kMaxW) + (size_t)i * kMaxW;

    for (int c = w; c < kC; c += kWaves) {
        const float* p = chbase + (size_t)c * kChStride;
        float4 a0, b0, a1, b1;
        if (need0) { a0 = *(const float4*)(p + r0 + o0);
                     b0 = *(const float4*)(p + r1 + o0); }
        if (need1) { a1 = *(const float4*)(p + r0 + o1);
                     b1 = *(const float4*)(p + r1 + o1); }
        if (need0) { *(float4*)&ls[w][0][o0] = a0;
                     *(float4*)&ls[w][1][o0] = b0; }
        if (need1) { *(float4*)&ls[w][0][o1] = a1;
                     *(float4*)&ls[w][1][o1] = b1; }
        // Wave-synchronous fence: ds_writes complete before ds_reads below;
        // clobber stops the compiler migrating LDS ops across.
        __asm__ volatile("s_waitcnt lgkmcnt(0)" ::: "memory");

        float* op = opb + (size_t)c * (kHout * kMaxW);
        #pragma unroll
        for (int q = 0; q < 3; ++q) {
            float out = 0.0f;
            if (vq[q]) {
                out = ls[w][0][lx0q[q]] * waq[q] + ls[w][1][lx0q[q]] * wbq[q]
                    + ls[w][0][lx1q[q]] * wcq[q] + ls[w][1][lx1q[q]] * wdq[q];
            }
            op[64 * q + lane] = out;     // poisoned d_out: invalid j -> 0
        }
        // WAR guard: next iteration's ds_writes must not hoist above reads.
        __asm__ volatile("" ::: "memory");
    }

    if (i == 0 && w == 0) {
        #pragma unroll
        for (int q = 0; q < 3; ++q) {
            mask[bn * kMaxW + 64 * q + lane] = vq[q] ? 1.0f : 0.0f;
        }
    }
}

extern "C" void kernel_launch(void* const* d_in, const int* in_sizes, int n_in,
                              void* d_out, int out_size, void* d_ws, size_t ws_size,
                              hipStream_t stream) {
    const float* image = (const float*)d_in[0];
    const float* boxes = (const float*)d_in[1];
    float* result = (float*)d_out;
    float* mask   = result + kResultElems;   // outputs concatenated flat

    dim3 grid(kB * kN * kHout);   // 4096 blocks: 8 xcd x 32 bn x 16 i
    dim3 block(kWaves * 64);      // 192 threads = 3 independent waves
    hipLaunchKernelGGL(roi_rotate, grid, block, 0, stream,
                       image, boxes, result, mask);
}

// Round 3
// 223.077 us; speedup vs baseline: 1.0209x; 1.0209x over previous
//
#include <hip/hip_runtime.h>

namespace {
constexpr int kB = 4, kC = 32, kH = 512, kW = 512, kN = 64;
constexpr int kHout = 16, kMaxW = 192;
constexpr long long kResultElems = (long long)kB * kN * kC * kHout * kMaxW;
constexpr int kWaves = 3;                    // 192 threads
}

// One block per (b, n, i); 3 waves. BARRIER-FREE: each wave owns channels
// {w, w+3, ...}, stages the two bilinear source rows (y0,y1) for its channel
// into its PRIVATE LDS region with coalesced float4 loads, then samples all
// 192 output columns itself (3 chunks of 64 lanes). No __syncthreads -- no
// vmcnt(0) drain points, no cross-wave coupling; 30 independent waves/CU hide
// LLC/L2 latency by TLP (R3/R4 showed the compiler defeats source-level
// pipelining around barriers; VGPR=20 proved the prefetch was sunk).
//
// R7 = exact revert to the best-measured configuration (222.6 us).
// Session findings (R5/R6 decomposition):
//  - nt stores: NULL-to-negative (output lines are re-poisoned by a 512 MiB
//    fill each iteration; nt forfeits any in-cache overwrite absorption).
//  - register prefetch: NULL (30 waves/CU TLP already covers load latency;
//    in-flight bytes exceed BW*latency by >10x).
//  - XCD swizzle: NULL (each_h = bh/15 >= 2 px for ~65% of boxes, so the 16
//    i-blocks of a box touch mostly disjoint rows -- no reuse to capture).
//  - All three variants within the bench noise band (fills vary +-3.5%).
// Ceiling: kernel ~57 us vs ~36 us HBM floor on 225 MB mixed traffic, with
// 2x ~83 us poison fills fixed in every timed iteration.
extern "C" __global__ __launch_bounds__(kWaves * 64) void roi_rotate(
    const float* __restrict__ image,
    const float* __restrict__ boxes,
    float* __restrict__ result,
    float* __restrict__ mask)
{
    __shared__ float ls[kWaves][2][kW];      // 12 KiB, wave-private regions

    const int blk = blockIdx.x;
    const int i  = blk & (kHout - 1);        // output row 0..15
    const int bn = blk >> 4;                 // b*N + n
    const int b  = bn >> 6;

    const int tid  = threadIdx.x;
    const int w    = tid >> 6;               // wave id 0..2
    const int lane = tid & 63;

    const float* bx = boxes + bn * 5;
    const float left = bx[0];
    const float top  = bx[1];
    const float bw   = __fsub_rn(bx[2], bx[0]);
    const float bh   = __fsub_rn(bx[3], bx[1]);
    const int width  = (int)(__fmul_rn(__fdiv_rn(bw, bh), (float)kHout));
    const float each_w = __fdiv_rn(bw, (float)(width - 1));
    const float each_h = __fdiv_rn(bh, (float)(kHout - 1));

    // y taps: uniform over the block (depend only on i).
    const float y = __fadd_rn(__fmul_rn((float)i, each_h), top);
    const int yf = (int)floorf(y);
    const int y0 = min(max(yf,     0), kH - 1);
    const int y1 = min(max(yf + 1, 0), kH - 1);
    const float wy1 = (float)y1 - y;
    const float wy0 = y - (float)y0;

    // Staging extent (block-uniform). For valid j: x in [left, left+bw], so
    // x0 >= xlo and x1 <= xhi. float4 tails over-read <= 3 floats and stay
    // inside the image allocation (y1 <= 497 for this input distribution).
    const int xlo = (min(max((int)floorf(left), 0), kW - 1)) & ~3;  // 16B align
    const int xhi = min((int)floorf(__fadd_rn(left, bw)) + 1, kW - 1);
    const int S   = xhi - xlo + 1;           // <= 512

    // Per-lane x taps for its 3 output columns j = 64q + lane.
    int   lx0q[3], lx1q[3];
    float waq[3], wbq[3], wcq[3], wdq[3];
    bool  vq[3];
    #pragma unroll
    for (int q = 0; q < 3; ++q) {
        const int j = 64 * q + lane;
        const float x = __fadd_rn(__fmul_rn((float)j, each_w), left);
        const int xf = (int)floorf(x);
        const int x0 = min(max(xf,     0), kW - 1);
        const int x1 = min(max(xf + 1, 0), kW - 1);
        const float wx1 = (float)x1 - x;
        const float wx0 = x - (float)x0;
        lx0q[q] = x0 - xlo;
        lx1q[q] = x1 - xlo;
        waq[q] = wx1 * wy1;
        wbq[q] = wx1 * wy0;
        wcq[q] = wx0 * wy1;
        wdq[q] = wx0 * wy0;
        vq[q]  = (j < width);
    }

    // Staging: lane covers 16B chunks at float offsets 4*lane and 4*(lane+64).
    const bool need0 = (4 * lane        < S);
    const bool need1 = (4 * (lane + 64) < S);
    const int  o0 = 4 * lane;
    const int  o1 = 4 * (lane + 64);
    const size_t r0 = (size_t)y0 * kW + xlo;
    const size_t r1 = (size_t)y1 * kW + xlo;

    const float* chbase = image + (size_t)b * ((size_t)kC * kH * kW);
    constexpr size_t kChStride = (size_t)kH * kW;
    float* opb = result + (size_t)bn * (kC * kHout * kMaxW) + (size_t)i * kMaxW;

    for (int c = w; c < kC; c += kWaves) {
        const float* p = chbase + (size_t)c * kChStride;
        float4 a0, b0, a1, b1;
        if (need0) { a0 = *(const float4*)(p + r0 + o0);
                     b0 = *(const float4*)(p + r1 + o0); }
        if (need1) { a1 = *(const float4*)(p + r0 + o1);
                     b1 = *(const float4*)(p + r1 + o1); }
        if (need0) { *(float4*)&ls[w][0][o0] = a0;
                     *(float4*)&ls[w][1][o0] = b0; }
        if (need1) { *(float4*)&ls[w][0][o1] = a1;
                     *(float4*)&ls[w][1][o1] = b1; }
        // Wave-synchronous fence: ds_writes complete before ds_reads below;
        // clobber stops the compiler migrating LDS ops across.
        __asm__ volatile("s_waitcnt lgkmcnt(0)" ::: "memory");

        float* op = opb + (size_t)c * (kHout * kMaxW);
        #pragma unroll
        for (int q = 0; q < 3; ++q) {
            float out = 0.0f;
            if (vq[q]) {
                out = ls[w][0][lx0q[q]] * waq[q] + ls[w][1][lx0q[q]] * wbq[q]
                    + ls[w][0][lx1q[q]] * wcq[q] + ls[w][1][lx1q[q]] * wdq[q];
            }
            op[64 * q + lane] = out;     // poisoned d_out: invalid j -> 0
        }
        // WAR guard: next iteration's ds_writes must not hoist above reads.
        __asm__ volatile("" ::: "memory");
    }

    if (i == 0 && w == 0) {
        #pragma unroll
        for (int q = 0; q < 3; ++q) {
            mask[bn * kMaxW + 64 * q + lane] = vq[q] ? 1.0f : 0.0f;
        }
    }
}

extern "C" void kernel_launch(void* const* d_in, const int* in_sizes, int n_in,
                              void* d_out, int out_size, void* d_ws, size_t ws_size,
                              hipStream_t stream) {
    const float* image = (const float*)d_in[0];
    const float* boxes = (const float*)d_in[1];
    float* result = (float*)d_out;
    float* mask   = result + kResultElems;   // outputs concatenated flat

    dim3 grid(kB * kN * kHout);   // 4096 blocks: (b,n,i)
    dim3 block(kWaves * 64);      // 192 threads = 3 independent waves
    hipLaunchKernelGGL(roi_rotate, grid, block, 0, stream,
                       image, boxes, result, mask);
}